// Round 7
// baseline (238.337 us; speedup 1.0000x reference)
//
#include <hip/hip_runtime.h>

typedef float f32x4 __attribute__((ext_vector_type(4)));

#define DIM 512

// DPP cross-lane (VALU pipe): xor1, xor2, half-mirror, row-mirror; + one
// ds_swizzle xor16 (BitMode, stays inside the 32-group) = 32-lane allreduce.
template <int CTRL>
__device__ __forceinline__ float dpp_mov(float x) {
    return __int_as_float(
        __builtin_amdgcn_update_dpp(0, __float_as_int(x), CTRL, 0xF, 0xF, true));
}
__device__ __forceinline__ float red32_add(float x) {
    x += dpp_mov<0xB1>(x);
    x += dpp_mov<0x4E>(x);
    x += dpp_mov<0x141>(x);
    x += dpp_mov<0x140>(x);
    x += __int_as_float(__builtin_amdgcn_ds_swizzle(__float_as_int(x), (16 << 10) | 0x1f));
    return x;
}
__device__ __forceinline__ float red32_max(float x) {
    x = fmaxf(x, dpp_mov<0xB1>(x));
    x = fmaxf(x, dpp_mov<0x4E>(x));
    x = fmaxf(x, dpp_mov<0x141>(x));
    x = fmaxf(x, dpp_mov<0x140>(x));
    x = fmaxf(x, __int_as_float(__builtin_amdgcn_ds_swizzle(__float_as_int(x), (16 << 10) | 0x1f)));
    return x;
}

// ---------------- Pass 1: per-row threshold tau ----------------
// One row-pair per wave (lanes 0-31 -> row 2p, 32-63 -> row 2p+1), 16
// elements/lane. Read-only streaming; writes only tau (2 floats/wave).
// Michelot from tau0 = max-1 (valid lower bound since p_max <= 1): support
// sets nested & shrinking -> exact finite convergence when counts stabilize.
__global__ __launch_bounds__(256) void tau_kernel(
    const float* __restrict__ x, float* __restrict__ tau, int batch) {
    const int wv   = threadIdx.x >> 6;
    const int lane = threadIdx.x & 63;
    const int half = lane >> 5;
    const int l    = lane & 31;
    const int p    = blockIdx.x * 4 + wv;          // row-pair index
    if (2 * p >= batch) return;

    const f32x4* xp = reinterpret_cast<const f32x4*>(x);
    const size_t ro = (size_t)(2 * p + half) * (DIM / 4) + l;
    f32x4 v0 = xp[ro], v1 = xp[ro + 32], v2 = xp[ro + 64], v3 = xp[ro + 96];

    float z[16] = {v0.x, v0.y, v0.z, v0.w, v1.x, v1.y, v1.z, v1.w,
                   v2.x, v2.y, v2.z, v2.w, v3.x, v3.y, v3.z, v3.w};

    float m = z[0];
#pragma unroll
    for (int j = 1; j < 16; ++j) m = fmaxf(m, z[j]);
    m = red32_max(m);
    float t = m - 1.0f;

    int kp0 = -1, kp1 = -1;
    for (int it = 0; it < 32; ++it) {
        float S = 0.f;
        int K0 = 0, K1 = 0;
#pragma unroll
        for (int j = 0; j < 16; ++j) {
            const bool in = z[j] > t;
            const unsigned long long b = __ballot(in);
            K0 += __popc((unsigned)b);
            K1 += __popc((unsigned)(b >> 32));
            S += in ? z[j] : 0.f;
        }
        S = red32_add(S);
        if (K0 == kp0 && K1 == kp1) break;     // sets stable -> fixed point
        kp0 = K0; kp1 = K1;
        const float K = (float)(half ? K1 : K0);
        t = (S - 1.0f) * __builtin_amdgcn_rcpf(K);   // K >= 1 (max in set)
    }

    if (l == 0) tau[2 * p + half] = t;         // lanes 0 and 32 write
}

// ---------------- Pass 2: elementwise apply ----------------
// out = max(0, x - tau[row]). Pure streaming: 4 independent f32x4
// load/compute/store chains per thread, copy-kernel issue pattern.
// x is L3-warm from pass 1.
__global__ __launch_bounds__(256) void apply_kernel(
    const float* __restrict__ x, const float* __restrict__ tau,
    float* __restrict__ out) {
    const f32x4* xp = reinterpret_cast<const f32x4*>(x);
    f32x4*       op = reinterpret_cast<f32x4*>(out);
    const size_t base = (size_t)blockIdx.x * 1024 + threadIdx.x;
#pragma unroll
    for (int j = 0; j < 4; ++j) {
        const size_t idx = base + (size_t)j * 256;
        const float  t   = tau[idx >> 7];      // row = f32x4-index / 128
        const f32x4  v   = xp[idx];
        f32x4 o;
        o.x = fmaxf(0.f, v.x - t);
        o.y = fmaxf(0.f, v.y - t);
        o.z = fmaxf(0.f, v.z - t);
        o.w = fmaxf(0.f, v.w - t);
        op[idx] = o;
    }
}

extern "C" void kernel_launch(void* const* d_in, const int* in_sizes, int n_in,
                              void* d_out, int out_size, void* d_ws, size_t ws_size,
                              hipStream_t stream) {
    const float* x   = (const float*)d_in[0];
    float*       out = (float*)d_out;
    float*       tau = (float*)d_ws;               // 65536 floats = 256 KB
    const int batch  = in_sizes[0] / DIM;          // 65536

    const int pairs  = batch >> 1;                 // 32768 waves, 1 pair each
    tau_kernel<<<(pairs + 3) / 4, 256, 0, stream>>>(x, tau, batch);

    const int nvec   = batch * (DIM / 4);          // 8,388,608 f32x4
    apply_kernel<<<nvec / 1024, 256, 0, stream>>>(x, tau, out);
}